// Round 6
// baseline (873.660 us; speedup 1.0000x reference)
//
#include <hip/hip_runtime.h>
#include <math.h>

#define NN 8192
#define NE 8

typedef float f32x4 __attribute__((ext_vector_type(4)));

// d_ws layout:
//   [0, 440)            : double sums[55]
//   [512, 512+65536)    : u64 key[8192]   (prob_bits<<16 | (8191-n)<<3 | idx)
//   [66048, 66048+32768): int rank[8192]
#define WS_KEY_OFF  512
#define WS_RANK_OFF (512 + 65536)

// Wave (64-lane) sum-reduce of a double, lane0 stores to part[q][wave]
#define WREDUCE(q, expr)                              \
    do {                                              \
        double v_ = (expr);                           \
        v_ += __shfl_down(v_, 32);                    \
        v_ += __shfl_down(v_, 16);                    \
        v_ += __shfl_down(v_, 8);                     \
        v_ += __shfl_down(v_, 4);                     \
        v_ += __shfl_down(v_, 2);                     \
        v_ += __shfl_down(v_, 1);                     \
        if (lane == 0) part[q][wv] = v_;              \
    } while (0)

// Zero the two big output arrays: exactly 50,331,648 float4s (the 4 trailing
// scalars are fully written by kfin). 2^20 threads x 48 fully-unrolled,
// compile-time-stride stores: max write ILP, no loop-carried address math.
#define FILL_BLOCKS 4096
#define FILL_THREADS ((size_t)FILL_BLOCKS * 256)  // 2^20
#define FILL_ITERS 48                             // 2^20 * 48 = 50,331,648

__global__ __launch_bounds__(256) void kzero_kernel(f32x4* __restrict__ out) {
    const f32x4 z = {0.f, 0.f, 0.f, 0.f};
    const size_t tid = (size_t)blockIdx.x * 256 + threadIdx.x;
#pragma unroll
    for (int g = 0; g < FILL_ITERS; ++g)
        out[(size_t)g * FILL_THREADS + tid] = z;
}

__global__ __launch_bounds__(256) void krow_kernel(const float* __restrict__ logits,
                                                   double* __restrict__ sums,
                                                   unsigned long long* __restrict__ key) {
    __shared__ double part[55][4];
    const int n = blockIdx.x * 256 + threadIdx.x;  // 0..8191
    const int lane = threadIdx.x & 63;
    const int wv = threadIdx.x >> 6;

    // Load one row of 8 raw logits (two float4s, coalesced)
    const float4* lp = reinterpret_cast<const float4*>(logits) + (size_t)n * 2;
    float4 a = lp[0];
    float4 b = lp[1];
    float lr[NE] = {a.x, a.y, a.z, a.w, b.x, b.y, b.z, b.w};

    // raw stats for std (ddof=1 over all N*E raw logits)
    double raw_s = 0.0, raw_q = 0.0;
#pragma unroll
    for (int e = 0; e < NE; ++e) {
        raw_s += (double)lr[e];
        raw_q += (double)lr[e] * (double)lr[e];
    }

    // clamp + temperature (f32, matching reference exactly)
    float l[NE];
#pragma unroll
    for (int e = 0; e < NE; ++e)
        l[e] = fminf(fmaxf(lr[e], -10.0f), 10.0f) / 1.5f;

    float m = l[0];
#pragma unroll
    for (int e = 1; e < NE; ++e) m = fmaxf(m, l[e]);

    // softmax in f64 (diffs taken in f32 like the reference, exp/sum in f64)
    double ex[NE], s = 0.0;
#pragma unroll
    for (int e = 0; e < NE; ++e) {
        ex[e] = exp((double)(l[e] - m));
        s += ex[e];
    }
    double p[NE];
    float pf[NE];
#pragma unroll
    for (int e = 0; e < NE; ++e) {
        p[e] = ex[e] / s;
        pf[e] = (float)p[e];  // near-correctly-rounded f32 probs
    }

    // argmax with first-max semantics on f32 probs (matches jnp.argmax)
    int idx = 0;
    float best = pf[0];
#pragma unroll
    for (int e = 1; e < NE; ++e)
        if (pf[e] > best) { best = pf[e]; idx = e; }

    double lse = (double)m + log(s);

    // sort key: prob desc primary, index asc secondary (stable argsort(-prob))
    unsigned int pb = __float_as_uint(best);  // prob > 0 => bits monotone
    key[n] = ((unsigned long long)pb << 16) |
             ((unsigned long long)(8191 - n) << 3) | (unsigned int)idx;

    // 55 wave-reductions -> LDS -> one global atomic per block per quantity
    WREDUCE(0, lse * lse);
#pragma unroll
    for (int e = 0; e < NE; ++e) WREDUCE(1 + e, p[e]);
#pragma unroll
    for (int e = 0; e < NE; ++e) WREDUCE(9 + e, (idx == e) ? 1.0 : 0.0);
    WREDUCE(17, raw_s);
    WREDUCE(18, raw_q);
    {
        int q = 19;
#pragma unroll
        for (int e = 0; e < NE; ++e)
#pragma unroll
            for (int f = 0; f < NE; ++f)
                if (f >= e) { WREDUCE(q, (double)l[e] * (double)l[f]); ++q; }
    }
    __syncthreads();
    if (threadIdx.x < 55) {
        double t = part[threadIdx.x][0] + part[threadIdx.x][1] +
                   part[threadIdx.x][2] + part[threadIdx.x][3];
        atomicAdd(&sums[threadIdx.x], t);
    }
}

__global__ void kfin_kernel(const double* __restrict__ sums, float* __restrict__ outs) {
    if (threadIdx.x != 0 || blockIdx.x != 0) return;
    const double Nd = (double)NN;
    double z_loss = sums[0] / Nd;

    double aux = 0.0;
    for (int e = 0; e < NE; ++e)
        aux += (sums[9 + e] / Nd) * (sums[1 + e] / Nd);
    aux *= (double)NE;

    double S[NE][NE];
    int q = 19;
    for (int e = 0; e < NE; ++e)
        for (int f = e; f < NE; ++f) {
            S[e][f] = sums[q];
            S[f][e] = sums[q];
            ++q;
        }
    double nrm[NE];
    for (int e = 0; e < NE; ++e) nrm[e] = fmax(sqrt(S[e][e]), 1e-12);
    double dv = 0.0;
    for (int e = 0; e < NE; ++e)
        for (int f = 0; f < NE; ++f)
            if (e != f) {
                double c = S[e][f] / (nrm[e] * nrm[f]);
                dv += c * c;
            }
    dv /= (double)(NE * (NE - 1));

    const double M = Nd * (double)NE;
    double var = (sums[18] - sums[17] * sums[17] / M) / (M - 1.0);

    outs[0] = (float)z_loss;
    outs[1] = (float)aux;
    outs[2] = (float)dv;
    outs[3] = (float)sqrt(var);
}

// Partial ranks: grid (32 row-blocks, 32 m-chunks). Each block stages a
// 256-key chunk in LDS; each thread counts same-expert keys strictly greater.
__global__ __launch_bounds__(256) void krank_kernel(const unsigned long long* __restrict__ key,
                                                    int* __restrict__ rank) {
    __shared__ unsigned long long kk[256];
    const int tid = threadIdx.x;
    const int n = blockIdx.x * 256 + tid;
    kk[tid] = key[blockIdx.y * 256 + tid];
    __syncthreads();
    const unsigned long long kn = key[n];
    const unsigned int e = (unsigned int)(kn & 7ull);
    int cnt = 0;
#pragma unroll 8
    for (int j = 0; j < 256; ++j) {
        unsigned long long km = kk[j];
        cnt += (int)(((km & 7ull) == e) & (km > kn));
    }
    if (cnt) atomicAdd(&rank[n], cnt);
}

__global__ __launch_bounds__(256) void kscatter_kernel(const unsigned long long* __restrict__ key,
                                                       const int* __restrict__ rank,
                                                       float* __restrict__ out, int Ccap) {
    const int n = blockIdx.x * 256 + threadIdx.x;
    const unsigned long long kn = key[n];
    const int e = (int)(kn & 7ull);
    const float p = __uint_as_float((unsigned int)(kn >> 16));
    const int r = rank[n];
    if (r < Ccap) {
        size_t off = ((size_t)n * NE + e) * (size_t)Ccap + (size_t)r;
        out[off] = 1.0f;                                   // dispatch
        out[(size_t)NN * NE * Ccap + off] = p;             // combine
    }
}

extern "C" void kernel_launch(void* const* d_in, const int* in_sizes, int n_in,
                              void* d_out, int out_size, void* d_ws, size_t ws_size,
                              hipStream_t stream) {
    const float* logits = (const float*)d_in[1];  // inputs: X, logits
    float* out = (float*)d_out;

    const int Ccap = (out_size - 4) / (2 * NN * NE);  // 1536
    const size_t big = (size_t)2 * NN * NE * (size_t)Ccap;

    double* sums = (double*)d_ws;
    unsigned long long* key = (unsigned long long*)((char*)d_ws + WS_KEY_OFF);
    int* rank = (int*)((char*)d_ws + WS_RANK_OFF);

    // Small ws clear (sums + rank): tiny, leave to the driver blit.
    (void)hipMemsetAsync(d_ws, 0, WS_RANK_OFF + NN * sizeof(int), stream);

    // Zero both big arrays (exactly 805 MB; kfin writes the 4 tail scalars).
    kzero_kernel<<<FILL_BLOCKS, 256, 0, stream>>>((f32x4*)out);

    krow_kernel<<<NN / 256, 256, 0, stream>>>(logits, sums, key);
    kfin_kernel<<<1, 64, 0, stream>>>(sums, out + big);
    krank_kernel<<<dim3(NN / 256, NN / 256), 256, 0, stream>>>(key, rank);
    kscatter_kernel<<<NN / 256, 256, 0, stream>>>(key, rank, out, Ccap);
}

// Round 9
// 813.102 us; speedup vs baseline: 1.0745x; 1.0745x over previous
//
#include <hip/hip_runtime.h>
#include <math.h>

#define NN 8192
#define NE 8

typedef float f32x4 __attribute__((ext_vector_type(4)));

// d_ws layout:
//   [0, 440)            : double sums[55]
//   [512, 512+65536)    : u64 key[8192]   (prob_bits<<16 | (8191-n)<<3 | idx)
//   [66048, 66048+32768): int rank[8192]
#define WS_KEY_OFF  512
#define WS_RANK_OFF (512 + 65536)

// Wave (64-lane) sum-reduce of a double, lane0 stores to part[q][wave]
#define WREDUCE(q, expr)                              \
    do {                                              \
        double v_ = (expr);                           \
        v_ += __shfl_down(v_, 32);                    \
        v_ += __shfl_down(v_, 16);                    \
        v_ += __shfl_down(v_, 8);                     \
        v_ += __shfl_down(v_, 4);                     \
        v_ += __shfl_down(v_, 2);                     \
        v_ += __shfl_down(v_, 1);                     \
        if (lane == 0) part[q][wv] = v_;              \
    } while (0)

// Fill, rocclr-style: flat flood dispatch, ONE 16B store per thread, no loop.
// (rocclr fillBufferAligned sustains 6.3 TB/s of HBM writes with this shape;
// all loop-based variants of ours pinned at ~2.5 TB/s.)
__global__ __launch_bounds__(256) void kzero_kernel(f32x4* __restrict__ out, size_t n4) {
    const size_t i = (size_t)blockIdx.x * 256 + threadIdx.x;
    if (i < n4) {
        const f32x4 z = {0.f, 0.f, 0.f, 0.f};
        out[i] = z;
    }
}

__global__ __launch_bounds__(256) void krow_kernel(const float* __restrict__ logits,
                                                   double* __restrict__ sums,
                                                   unsigned long long* __restrict__ key) {
    __shared__ double part[55][4];
    const int n = blockIdx.x * 256 + threadIdx.x;  // 0..8191
    const int lane = threadIdx.x & 63;
    const int wv = threadIdx.x >> 6;

    // Load one row of 8 raw logits (two float4s, coalesced)
    const float4* lp = reinterpret_cast<const float4*>(logits) + (size_t)n * 2;
    float4 a = lp[0];
    float4 b = lp[1];
    float lr[NE] = {a.x, a.y, a.z, a.w, b.x, b.y, b.z, b.w};

    // raw stats for std (ddof=1 over all N*E raw logits)
    double raw_s = 0.0, raw_q = 0.0;
#pragma unroll
    for (int e = 0; e < NE; ++e) {
        raw_s += (double)lr[e];
        raw_q += (double)lr[e] * (double)lr[e];
    }

    // clamp + temperature (f32, matching reference exactly)
    float l[NE];
#pragma unroll
    for (int e = 0; e < NE; ++e)
        l[e] = fminf(fmaxf(lr[e], -10.0f), 10.0f) / 1.5f;

    float m = l[0];
#pragma unroll
    for (int e = 1; e < NE; ++e) m = fmaxf(m, l[e]);

    // softmax in f64 (diffs taken in f32 like the reference, exp/sum in f64)
    double ex[NE], s = 0.0;
#pragma unroll
    for (int e = 0; e < NE; ++e) {
        ex[e] = exp((double)(l[e] - m));
        s += ex[e];
    }
    double p[NE];
    float pf[NE];
#pragma unroll
    for (int e = 0; e < NE; ++e) {
        p[e] = ex[e] / s;
        pf[e] = (float)p[e];  // near-correctly-rounded f32 probs
    }

    // argmax with first-max semantics on f32 probs (matches jnp.argmax)
    int idx = 0;
    float best = pf[0];
#pragma unroll
    for (int e = 1; e < NE; ++e)
        if (pf[e] > best) { best = pf[e]; idx = e; }

    double lse = (double)m + log(s);

    // sort key: prob desc primary, index asc secondary (stable argsort(-prob))
    unsigned int pb = __float_as_uint(best);  // prob > 0 => bits monotone
    key[n] = ((unsigned long long)pb << 16) |
             ((unsigned long long)(8191 - n) << 3) | (unsigned int)idx;

    // 55 wave-reductions -> LDS -> one global atomic per block per quantity
    WREDUCE(0, lse * lse);
#pragma unroll
    for (int e = 0; e < NE; ++e) WREDUCE(1 + e, p[e]);
#pragma unroll
    for (int e = 0; e < NE; ++e) WREDUCE(9 + e, (idx == e) ? 1.0 : 0.0);
    WREDUCE(17, raw_s);
    WREDUCE(18, raw_q);
    {
        int q = 19;
#pragma unroll
        for (int e = 0; e < NE; ++e)
#pragma unroll
            for (int f = 0; f < NE; ++f)
                if (f >= e) { WREDUCE(q, (double)l[e] * (double)l[f]); ++q; }
    }
    __syncthreads();
    if (threadIdx.x < 55) {
        double t = part[threadIdx.x][0] + part[threadIdx.x][1] +
                   part[threadIdx.x][2] + part[threadIdx.x][3];
        atomicAdd(&sums[threadIdx.x], t);
    }
}

__global__ void kfin_kernel(const double* __restrict__ sums, float* __restrict__ outs) {
    if (threadIdx.x != 0 || blockIdx.x != 0) return;
    const double Nd = (double)NN;
    double z_loss = sums[0] / Nd;

    double aux = 0.0;
    for (int e = 0; e < NE; ++e)
        aux += (sums[9 + e] / Nd) * (sums[1 + e] / Nd);
    aux *= (double)NE;

    double S[NE][NE];
    int q = 19;
    for (int e = 0; e < NE; ++e)
        for (int f = e; f < NE; ++f) {
            S[e][f] = sums[q];
            S[f][e] = sums[q];
            ++q;
        }
    double nrm[NE];
    for (int e = 0; e < NE; ++e) nrm[e] = fmax(sqrt(S[e][e]), 1e-12);
    double dv = 0.0;
    for (int e = 0; e < NE; ++e)
        for (int f = 0; f < NE; ++f)
            if (e != f) {
                double c = S[e][f] / (nrm[e] * nrm[f]);
                dv += c * c;
            }
    dv /= (double)(NE * (NE - 1));

    const double M = Nd * (double)NE;
    double var = (sums[18] - sums[17] * sums[17] / M) / (M - 1.0);

    outs[0] = (float)z_loss;
    outs[1] = (float)aux;
    outs[2] = (float)dv;
    outs[3] = (float)sqrt(var);
}

// Partial ranks: grid (32 row-blocks, 32 m-chunks). Each block stages a
// 256-key chunk in LDS; each thread counts same-expert keys strictly greater.
__global__ __launch_bounds__(256) void krank_kernel(const unsigned long long* __restrict__ key,
                                                    int* __restrict__ rank) {
    __shared__ unsigned long long kk[256];
    const int tid = threadIdx.x;
    const int n = blockIdx.x * 256 + tid;
    kk[tid] = key[blockIdx.y * 256 + tid];
    __syncthreads();
    const unsigned long long kn = key[n];
    const unsigned int e = (unsigned int)(kn & 7ull);
    int cnt = 0;
#pragma unroll 8
    for (int j = 0; j < 256; ++j) {
        unsigned long long km = kk[j];
        cnt += (int)(((km & 7ull) == e) & (km > kn));
    }
    if (cnt) atomicAdd(&rank[n], cnt);
}

__global__ __launch_bounds__(256) void kscatter_kernel(const unsigned long long* __restrict__ key,
                                                       const int* __restrict__ rank,
                                                       float* __restrict__ out, int Ccap) {
    const int n = blockIdx.x * 256 + threadIdx.x;
    const unsigned long long kn = key[n];
    const int e = (int)(kn & 7ull);
    const float p = __uint_as_float((unsigned int)(kn >> 16));
    const int r = rank[n];
    if (r < Ccap) {
        size_t off = ((size_t)n * NE + e) * (size_t)Ccap + (size_t)r;
        out[off] = 1.0f;                                   // dispatch
        out[(size_t)NN * NE * Ccap + off] = p;             // combine
    }
}

extern "C" void kernel_launch(void* const* d_in, const int* in_sizes, int n_in,
                              void* d_out, int out_size, void* d_ws, size_t ws_size,
                              hipStream_t stream) {
    const float* logits = (const float*)d_in[1];  // inputs: X, logits
    float* out = (float*)d_out;

    const int Ccap = (out_size - 4) / (2 * NN * NE);  // 1536
    const size_t big = (size_t)2 * NN * NE * (size_t)Ccap;

    double* sums = (double*)d_ws;
    unsigned long long* key = (unsigned long long*)((char*)d_ws + WS_KEY_OFF);
    int* rank = (int*)((char*)d_ws + WS_RANK_OFF);

    // Small ws clear (sums + rank): tiny, leave to the driver blit.
    (void)hipMemsetAsync(d_ws, 0, WS_RANK_OFF + NN * sizeof(int), stream);

    // Flood-dispatch fill: one 16B store per thread, rocclr-style.
    const size_t n4 = (size_t)out_size / 4;  // 50,331,649 (out_size % 4 == 0)
    const int fill_blocks = (int)((n4 + 255) / 256);  // 196,609
    kzero_kernel<<<fill_blocks, 256, 0, stream>>>((f32x4*)out, n4);

    krow_kernel<<<NN / 256, 256, 0, stream>>>(logits, sums, key);
    kfin_kernel<<<1, 64, 0, stream>>>(sums, out + big);
    krank_kernel<<<dim3(NN / 256, NN / 256), 256, 0, stream>>>(key, rank);
    kscatter_kernel<<<NN / 256, 256, 0, stream>>>(key, rank, out, Ccap);
}